// Round 7
// baseline (4808.518 us; speedup 1.0000x reference)
//
#include <hip/hip_runtime.h>
#include <hip/hip_fp16.h>
#include <cstddef>
#include <cstdint>

#define NSG   8
#define NPAIR 28
#define NBLK  36                 // 28 cross + 8 self cost matrices (unique storage)
#define NPT   1024
#define DIM   256
#define NROW  8192
#define NCH   32                 // 32-row chunks per matrix
#define LOG_N  6.9314718055994531f
#define LOG2E  1.4426950408889634f

// triu_indices(8,1) pairs, then 8 self pairs
__constant__ int c_pa[NBLK] = {0,0,0,0,0,0,0,1,1,1,1,1,1,2,2,2,2,2,3,3,3,3,4,4,4,5,5,6, 0,1,2,3,4,5,6,7};
__constant__ int c_pb[NBLK] = {1,2,3,4,5,6,7,2,3,4,5,6,7,3,4,5,6,7,4,5,6,7,5,6,7,6,7,7, 0,1,2,3,4,5,6,7};

__device__ __forceinline__ float wredMax(float v) {
#pragma unroll
  for (int o = 32; o > 0; o >>= 1) v = fmaxf(v, __shfl_xor(v, o, 64));
  return v;
}
__device__ __forceinline__ float wredSum(float v) {
#pragma unroll
  for (int o = 32; o > 0; o >>= 1) v += __shfl_xor(v, o, 64);
  return v;
}

__device__ __forceinline__ void cvt16(float4 A, float4 B, float* c) {
  const __half2* ha = (const __half2*)&A;
  const __half2* hb = (const __half2*)&B;
#pragma unroll
  for (int i = 0; i < 4; i++) {
    float2 f = __half22float2(ha[i]);
    c[2 * i] = f.x; c[2 * i + 1] = f.y;
  }
#pragma unroll
  for (int i = 0; i < 4; i++) {
    float2 f = __half22float2(hb[i]);
    c[8 + 2 * i] = f.x; c[8 + 2 * i + 1] = f.y;
  }
}

// ---- phase 0: grouping ----
__global__ void build_idx(const int* __restrict__ sg, int* __restrict__ idx, int* __restrict__ cnt) {
  int i = blockIdx.x * 256 + threadIdx.x;
  if (i >= NROW) return;
  int s = sg[i];
  int r = atomicAdd(&cnt[s], 1);
  idx[s * NPT + r] = i;
}

__global__ void gather_rows(const float* __restrict__ feat, const int* __restrict__ idx,
                            float* __restrict__ G, float* __restrict__ sq) {
  int row = blockIdx.x;
  int src = idx[row];
  float v = feat[(size_t)src * DIM + threadIdx.x];
  G[(size_t)row * DIM + threadIdx.x] = v;
  float p = wredSum(v * v);
  __shared__ float ws[4];
  if ((threadIdx.x & 63) == 0) ws[threadIdx.x >> 6] = p;
  __syncthreads();
  if (threadIdx.x == 0) sq[row] = 0.5f * (ws[0] + ws[1] + ws[2] + ws[3]);
}

// ---- phase 1: cost matrices (fp16) into C[mat]; mat = pair idx (<28) or 28+sg ----
__global__ __launch_bounds__(256) void cost_gemm(const float* __restrict__ G,
                                                 const float* __restrict__ sq,
                                                 __half* __restrict__ C) {
  __shared__ float As[8][128];
  __shared__ float Bt[8][128];
  int blk = blockIdx.x;
  int b = blk >> 6, t = blk & 63;
  int sa = c_pa[b], sb = c_pb[b];
  int i0 = (t >> 3) << 7, j0 = (t & 7) << 7;
  const float* Arows = G + (size_t)(sa * NPT + i0) * DIM;
  const float* Brows = G + (size_t)(sb * NPT + j0) * DIM;
  int tid = threadIdx.x;
  int ty = tid >> 4, tx = tid & 15;
  float acc[8][8];
#pragma unroll
  for (int r = 0; r < 8; r++)
#pragma unroll
    for (int q = 0; q < 8; q++) acc[r][q] = 0.f;

  int lrow = tid >> 1, lk4 = (tid & 1) << 2;
  for (int k0 = 0; k0 < DIM; k0 += 8) {
    __syncthreads();
    float4 av = *(const float4*)(Arows + (size_t)lrow * DIM + k0 + lk4);
    float4 bv = *(const float4*)(Brows + (size_t)lrow * DIM + k0 + lk4);
    As[lk4 + 0][lrow] = av.x; As[lk4 + 1][lrow] = av.y; As[lk4 + 2][lrow] = av.z; As[lk4 + 3][lrow] = av.w;
    Bt[lk4 + 0][lrow] = bv.x; Bt[lk4 + 1][lrow] = bv.y; Bt[lk4 + 2][lrow] = bv.z; Bt[lk4 + 3][lrow] = bv.w;
    __syncthreads();
#pragma unroll
    for (int kk = 0; kk < 8; kk++) {
      float4 a0 = *(const float4*)&As[kk][ty << 3];
      float4 a1 = *(const float4*)&As[kk][(ty << 3) + 4];
      float4 b0 = *(const float4*)&Bt[kk][tx << 3];
      float4 b1 = *(const float4*)&Bt[kk][(tx << 3) + 4];
      float ar[8] = {a0.x, a0.y, a0.z, a0.w, a1.x, a1.y, a1.z, a1.w};
      float br[8] = {b0.x, b0.y, b0.z, b0.w, b1.x, b1.y, b1.z, b1.w};
#pragma unroll
      for (int r = 0; r < 8; r++)
#pragma unroll
        for (int q = 0; q < 8; q++) acc[r][q] = fmaf(ar[r], br[q], acc[r][q]);
    }
  }
  __half* dst = C + ((size_t)b << 20);
  float sqa[8], sqb[8];
#pragma unroll
  for (int r = 0; r < 8; r++) sqa[r] = sq[sa * NPT + i0 + (ty << 3) + r];
#pragma unroll
  for (int q = 0; q < 8; q++) sqb[q] = sq[sb * NPT + j0 + (tx << 3) + q];
#pragma unroll
  for (int r = 0; r < 8; r++) {
    __half* drow = dst + (size_t)(i0 + (ty << 3) + r) * NPT + j0 + (tx << 3);
    union { float4 f4; __half h[8]; } o;
#pragma unroll
    for (int q = 0; q < 8; q++)
      o.h[q] = __float2half_rn(fmaxf(sqa[r] + sqb[q] - acc[r][q], 0.f));
    *(float4*)drow = o.f4;
  }
}

// ---- phase 2: one Sinkhorn step, unique C read ONCE ----
// pot layout: [f: 0..27][g: 28..55][s: 56..63] rows of 1024 floats.
// Block (mat, chunk): 32 rows. Lane owns 16 consecutive cols.
// Row phase: f (cross) / s (diag) via wave-reduced LSE of (h - C).
// Col phase (cross): per-lane online LSE of (f_prev - C) -> per-chunk partials.
__global__ __launch_bounds__(256) void sink_step(
    const __half* __restrict__ C, const float* __restrict__ pot_cur,
    float* __restrict__ pot_nxt, float2* __restrict__ part,
    float eps, float csS, float cmS) {
  __shared__ float2 cmrg[4][NPT];   // 32 KB cross-wave col merge
  const int b = blockIdx.x;
  const int mat = b >> 5, chunk = b & 31;
  const bool cross = (mat < NPAIR);
  const int wave = threadIdx.x >> 6, lane = threadIdx.x & 63;
  const float c0 = LOG2E / eps;
  const int out_slot = cross ? mat : (mat + 28);
  const float cs = cross ? 0.f : csS;
  const float cm = cross ? 1.f : cmS;

  // h = mate potential (g for cross, s for diag) at this lane's 16 columns
  const float* hp = pot_cur + ((mat + 28) << 10) + (lane << 4);
  float h[16];
  {
    float4 h0 = ((const float4*)hp)[0], h1 = ((const float4*)hp)[1];
    float4 h2 = ((const float4*)hp)[2], h3 = ((const float4*)hp)[3];
    h[0]=h0.x; h[1]=h0.y; h[2]=h0.z; h[3]=h0.w;
    h[4]=h1.x; h[5]=h1.y; h[6]=h1.z; h[7]=h1.w;
    h[8]=h2.x; h[9]=h2.y; h[10]=h2.z; h[11]=h2.w;
    h[12]=h3.x; h[13]=h3.y; h[14]=h3.z; h[15]=h3.w;
  }

  const int row0 = chunk << 5;
  const __half* Cb = C + ((size_t)mat << 20) + ((size_t)row0 << 10) + (lane << 4);

  float CM[16], CL[16];
#pragma unroll
  for (int t = 0; t < 16; t++) { CM[t] = -3.4e38f; CL[t] = 0.f; }

  // prefetch row for k=0
  const float4* rp0 = (const float4*)(Cb + ((size_t)wave << 10));
  float4 a0 = rp0[0], a1 = rp0[1];
  float4 b0 = a0, b1 = a1;

  for (int k = 0; k < 8; k++) {
    const int row = row0 + (k << 2) + wave;
    if (k < 7) {
      const float4* rp = (const float4*)(Cb + ((size_t)(((k + 1) << 2) + wave) << 10));
      b0 = rp[0]; b1 = rp[1];
    }
    float c[16];
    cvt16(a0, a1, c);

    // ---- row LSE: softmin_j (h_j - C_row,j) ----
    float a[16];
    float m = -3.4e38f;
#pragma unroll
    for (int t = 0; t < 16; t++) { a[t] = h[t] - c[t]; m = fmaxf(m, a[t]); }
    m = wredMax(m);
    float ss = 0.f;
#pragma unroll
    for (int t = 0; t < 16; t++) ss += exp2f((a[t] - m) * c0);
    ss = wredSum(ss);
    if (lane == 0) {
      const float sm = -(m + eps * (__logf(ss) - LOG_N));
      pot_nxt[(out_slot << 10) + row] = cs * pot_cur[(out_slot << 10) + row] + cm * sm;
    }

    // ---- col online LSE (cross only): (f_prev_row - C_row,j) per lane column ----
    if (cross) {
      const float fr = pot_cur[(mat << 10) + row];   // wave-uniform
#pragma unroll
      for (int t = 0; t < 16; t++) {
        const float av = fr - c[t];
        const float d = av - CM[t];
        const float e = exp2f(-fabsf(d) * c0);  // d=+inf on first row -> e=0 -> CL=1
        const float w1 = d > 0.f ? e : 1.f;
        const float w2 = d > 0.f ? 1.f : e;
        CL[t] = fmaf(CL[t], w1, w2);
        CM[t] = fmaxf(CM[t], av);
      }
    }
    a0 = b0; a1 = b1;
  }

  if (cross) {
    // merge 4 waves' column states via LDS, write per-chunk partial
#pragma unroll
    for (int t = 0; t < 16; t++) cmrg[wave][(lane << 4) + t] = make_float2(CM[t], CL[t]);
    __syncthreads();
    const int colBase = threadIdx.x << 2;
    float2 outp[4];
#pragma unroll
    for (int cc = 0; cc < 4; cc++) {
      const int col = colBase + cc;
      float2 v0 = cmrg[0][col], v1 = cmrg[1][col], v2 = cmrg[2][col], v3 = cmrg[3][col];
      float M = fmaxf(fmaxf(v0.x, v1.x), fmaxf(v2.x, v3.x));
      float L = v0.y * exp2f((v0.x - M) * c0) + v1.y * exp2f((v1.x - M) * c0) +
                v2.y * exp2f((v2.x - M) * c0) + v3.y * exp2f((v3.x - M) * c0);
      outp[cc] = make_float2(M, L);
    }
    float2* pdst = part + (((size_t)((mat << 5) | chunk)) << 10) + colBase;
    *(float4*)&pdst[0] = *(float4*)&outp[0];
    *(float4*)&pdst[2] = *(float4*)&outp[2];
  }
}

// ---- combine column partials into g (one thread per (pair, col)) ----
__global__ void combine_g(const float2* __restrict__ part, float* __restrict__ pot_nxt, float eps) {
  const int jg = blockIdx.x * 256 + threadIdx.x;   // 28*1024
  const int p = jg >> 10, j = jg & 1023;
  const float c0 = LOG2E / eps;
  const float2* pp = part + (((size_t)p << 5) << 10) + j;
  float2 v[NCH];
#pragma unroll
  for (int c = 0; c < NCH; c++) v[c] = pp[(size_t)c << 10];
  float M = v[0].x;
#pragma unroll
  for (int c = 1; c < NCH; c++) M = fmaxf(M, v[c].x);
  float L = 0.f;
#pragma unroll
  for (int c = 0; c < NCH; c++) L += v[c].y * exp2f((v[c].x - M) * c0);
  pot_nxt[((28 + p) << 10) + j] = -(M + eps * (__logf(L) - LOG_N));
}

// ---- phase 3: losses ----
__global__ void loss_pairs(const float* __restrict__ pot, float* __restrict__ out) {
  int pb = blockIdx.x;
  int si = c_pa[pb], sj = c_pb[pb];
  const float* fv = pot + (pb << 10);
  const float* gv = pot + ((28 + pb) << 10);
  const float* sa = pot + ((56 + si) << 10);
  const float* sb = pot + ((56 + sj) << 10);
  float acc = 0.f;
  for (int t = threadIdx.x; t < NPT; t += 256)
    acc += (fv[t] - sa[t]) + (gv[t] - sb[t]);
  acc = wredSum(acc);
  __shared__ float wsm[4];
  if ((threadIdx.x & 63) == 0) wsm[threadIdx.x >> 6] = acc;
  __syncthreads();
  if (threadIdx.x == 0) out[1 + pb] = (wsm[0] + wsm[1] + wsm[2] + wsm[3]) * (1.0f / NPT);
}

__global__ void loss_total(float* __restrict__ out) {
  int t = threadIdx.x;
  float x = (t < NPAIR) ? out[1 + t] : 0.f;
  x = wredSum(x);
  if (t == 0) out[0] = x / (float)NPAIR;
}

extern "C" void kernel_launch(void* const* d_in, const int* in_sizes, int n_in,
                              void* d_out, int out_size, void* d_ws, size_t ws_size,
                              hipStream_t stream) {
  const float* feat = (const float*)d_in[0];
  const int* sg = (const int*)d_in[1];
  float* out = (float*)d_out;
  char* ws = (char*)d_ws;

  size_t o = 0;
  __half* C = (__half*)(ws + o); o += (size_t)NBLK * NPT * NPT * 2;   // 72 MB unique
  float* G  = (float*)(ws + o); o += (size_t)NROW * DIM * 4;          // 8.4 MB
  float* sq = (float*)(ws + o); o += (size_t)NROW * 4;
  int* idx  = (int*)(ws + o); o += (size_t)NROW * 4;
  int* cnt  = (int*)(ws + o); o += 1024;
  float* pot[2];
  pot[0] = (float*)(ws + o); o += (size_t)64 * NPT * 4;               // 256 KB
  pot[1] = (float*)(ws + o); o += (size_t)64 * NPT * 4;
  float2* part = (float2*)(ws + o); o += (size_t)NPAIR * NCH * NPT * 8;  // 7.3 MB

  hipMemsetAsync(cnt, 0, 1024, stream);
  hipMemsetAsync(pot[0], 0, (size_t)64 * NPT * 4, stream);   // f0=g0=s0=0

  build_idx<<<NROW / 256, 256, 0, stream>>>(sg, idx, cnt);
  gather_rows<<<NROW, 256, 0, stream>>>(feat, idx, G, sq);
  cost_gemm<<<NBLK * 64, 256, 0, stream>>>(G, sq, C);

  // epsilon schedule (mirrors reference trace-time logic)
  float sched[256];
  int ns = 0;
  {
    double e = 256.0;
    const double ratio = 0.9 * 0.9;
    const double tgt = 1e-4 * 1e-4;
    while (e > tgt) { sched[ns++] = (float)e; e *= ratio; }
    sched[ns++] = (float)tgt;
  }
  const float epsT = sched[ns - 1];

  int cur = 0;
  for (int k = 0; k < ns; k++) {
    sink_step<<<NBLK * NCH, 256, 0, stream>>>(C, pot[cur], pot[1 - cur], part,
                                              sched[k], 0.5f, 0.5f);
    combine_g<<<NPAIR * NPT / 256, 256, 0, stream>>>(part, pot[1 - cur], sched[k]);
    cur ^= 1;
  }
  // final extrapolation at eps_target (s not blended)
  sink_step<<<NBLK * NCH, 256, 0, stream>>>(C, pot[cur], pot[1 - cur], part,
                                            epsT, 0.0f, 1.0f);
  combine_g<<<NPAIR * NPT / 256, 256, 0, stream>>>(part, pot[1 - cur], epsT);
  cur ^= 1;
  loss_pairs<<<NPAIR, 256, 0, stream>>>(pot[cur], out);
  loss_total<<<1, 64, 0, stream>>>(out);
}

// Round 8
// 3473.628 us; speedup vs baseline: 1.3843x; 1.3843x over previous
//
#include <hip/hip_runtime.h>
#include <hip/hip_fp16.h>
#include <cstddef>
#include <cstdint>

#define NSG   8
#define NPAIR 28
#define NBLK  36                 // unique cost products: 28 cross + 8 self
#define NPT   1024
#define DIM   256
#define NROW  8192
#define LOG_N  6.9314718055994531f
#define LOG2E  1.4426950408889634f

// triu_indices(8,1) pairs, then 8 self pairs
__constant__ int c_pa[NBLK] = {0,0,0,0,0,0,0,1,1,1,1,1,1,2,2,2,2,2,3,3,3,3,4,4,4,5,5,6, 0,1,2,3,4,5,6,7};
__constant__ int c_pb[NBLK] = {1,2,3,4,5,6,7,2,3,4,5,6,7,3,4,5,6,7,4,5,6,7,5,6,7,6,7,7, 0,1,2,3,4,5,6,7};

__device__ __forceinline__ float wredMax(float v) {
#pragma unroll
  for (int o = 32; o > 0; o >>= 1) v = fmaxf(v, __shfl_xor(v, o, 64));
  return v;
}
__device__ __forceinline__ float wredMin(float v) {
#pragma unroll
  for (int o = 32; o > 0; o >>= 1) v = fminf(v, __shfl_xor(v, o, 64));
  return v;
}
__device__ __forceinline__ float wredSum(float v) {
#pragma unroll
  for (int o = 32; o > 0; o >>= 1) v += __shfl_xor(v, o, 64);
  return v;
}

__device__ __forceinline__ void cvt16(float4 A, float4 B, float* c) {
  const __half2* ha = (const __half2*)&A;
  const __half2* hb = (const __half2*)&B;
#pragma unroll
  for (int i = 0; i < 4; i++) {
    float2 f = __half22float2(ha[i]);
    c[2 * i] = f.x; c[2 * i + 1] = f.y;
  }
#pragma unroll
  for (int i = 0; i < 4; i++) {
    float2 f = __half22float2(hb[i]);
    c[8 + 2 * i] = f.x; c[8 + 2 * i + 1] = f.y;
  }
}

__device__ __forceinline__ float ub(unsigned int w, int s) {
  return (float)((w >> s) & 0xffu);   // compiler lowers to v_cvt_f32_ubyteN
}

// ---- phase 0: grouping ----
__global__ void build_idx(const int* __restrict__ sg, int* __restrict__ idx, int* __restrict__ cnt) {
  int i = blockIdx.x * 256 + threadIdx.x;
  if (i >= NROW) return;
  int s = sg[i];
  int r = atomicAdd(&cnt[s], 1);
  idx[s * NPT + r] = i;
}

__global__ void gather_rows(const float* __restrict__ feat, const int* __restrict__ idx,
                            float* __restrict__ G, float* __restrict__ sq) {
  int row = blockIdx.x;
  int src = idx[row];
  float v = feat[(size_t)src * DIM + threadIdx.x];
  G[(size_t)row * DIM + threadIdx.x] = v;
  float p = wredSum(v * v);
  __shared__ float ws[4];
  if ((threadIdx.x & 63) == 0) ws[threadIdx.x >> 6] = p;
  __syncthreads();
  if (threadIdx.x == 0) sq[row] = 0.5f * (ws[0] + ws[1] + ws[2] + ws[3]);
}

// ---- phase 1: cost matrices (fp16) into Ch[b], b = unique product idx ----
__global__ __launch_bounds__(256) void cost_gemm(const float* __restrict__ G,
                                                 const float* __restrict__ sq,
                                                 __half* __restrict__ Ch) {
  __shared__ float As[8][128];
  __shared__ float Bt[8][128];
  int blk = blockIdx.x;
  int b = blk >> 6, t = blk & 63;
  int sa = c_pa[b], sb = c_pb[b];
  int i0 = (t >> 3) << 7, j0 = (t & 7) << 7;
  const float* Arows = G + (size_t)(sa * NPT + i0) * DIM;
  const float* Brows = G + (size_t)(sb * NPT + j0) * DIM;
  int tid = threadIdx.x;
  int ty = tid >> 4, tx = tid & 15;
  float acc[8][8];
#pragma unroll
  for (int r = 0; r < 8; r++)
#pragma unroll
    for (int q = 0; q < 8; q++) acc[r][q] = 0.f;

  int lrow = tid >> 1, lk4 = (tid & 1) << 2;
  for (int k0 = 0; k0 < DIM; k0 += 8) {
    __syncthreads();
    float4 av = *(const float4*)(Arows + (size_t)lrow * DIM + k0 + lk4);
    float4 bv = *(const float4*)(Brows + (size_t)lrow * DIM + k0 + lk4);
    As[lk4 + 0][lrow] = av.x; As[lk4 + 1][lrow] = av.y; As[lk4 + 2][lrow] = av.z; As[lk4 + 3][lrow] = av.w;
    Bt[lk4 + 0][lrow] = bv.x; Bt[lk4 + 1][lrow] = bv.y; Bt[lk4 + 2][lrow] = bv.z; Bt[lk4 + 3][lrow] = bv.w;
    __syncthreads();
#pragma unroll
    for (int kk = 0; kk < 8; kk++) {
      float4 a0 = *(const float4*)&As[kk][ty << 3];
      float4 a1 = *(const float4*)&As[kk][(ty << 3) + 4];
      float4 b0 = *(const float4*)&Bt[kk][tx << 3];
      float4 b1 = *(const float4*)&Bt[kk][(tx << 3) + 4];
      float ar[8] = {a0.x, a0.y, a0.z, a0.w, a1.x, a1.y, a1.z, a1.w};
      float br[8] = {b0.x, b0.y, b0.z, b0.w, b1.x, b1.y, b1.z, b1.w};
#pragma unroll
      for (int r = 0; r < 8; r++)
#pragma unroll
        for (int q = 0; q < 8; q++) acc[r][q] = fmaf(ar[r], br[q], acc[r][q]);
    }
  }
  __half* dst = Ch + ((size_t)b << 20);
  float sqa[8], sqb[8];
#pragma unroll
  for (int r = 0; r < 8; r++) sqa[r] = sq[sa * NPT + i0 + (ty << 3) + r];
#pragma unroll
  for (int q = 0; q < 8; q++) sqb[q] = sq[sb * NPT + j0 + (tx << 3) + q];
#pragma unroll
  for (int r = 0; r < 8; r++) {
    __half* drow = dst + (size_t)(i0 + (ty << 3) + r) * NPT + j0 + (tx << 3);
    union { float4 f4; __half h[8]; } o;
#pragma unroll
    for (int q = 0; q < 8; q++)
      o.h[q] = __float2half_rn(fmaxf(sqa[r] + sqb[q] - acc[r][q], 0.f));
    *(float4*)drow = o.f4;
  }
}

// ---- phase 1b: per-row u8 quantization into C8 slot (q = 8a+b layout; diag = 9a) ----
__global__ __launch_bounds__(256) void quant_row(const __half* __restrict__ Ch,
                                                 unsigned char* __restrict__ C8,
                                                 float2* __restrict__ rowScale) {
  const int blk = blockIdx.x;
  const int b = blk >> 4, rowblk = blk & 15;
  const int sa = c_pa[b], sb = c_pb[b];
  const int q = (sa == sb) ? 9 * sa : 8 * sa + sb;
  const __half* src = Ch + ((size_t)b << 20);
  unsigned char* dst = C8 + ((size_t)q << 20);
  const int wave = threadIdx.x >> 6, lane = threadIdx.x & 63;
  for (int jj = 0; jj < 16; jj++) {
    const int row = (rowblk << 6) + (jj << 2) + wave;
    const float4* s4 = (const float4*)(src + ((size_t)row << 10) + (lane << 4));
    float c[16];
    cvt16(s4[0], s4[1], c);
    float mn = c[0], mx = c[0];
#pragma unroll
    for (int t = 1; t < 16; t++) { mn = fminf(mn, c[t]); mx = fmaxf(mx, c[t]); }
    mn = wredMin(mn);
    mx = wredMax(mx);
    const float range = mx - mn;
    const float scale = (range > 1e-6f) ? range * (1.0f / 255.0f) : 1.0f;
    const float inv = (range > 1e-6f) ? 255.0f / range : 0.0f;
    unsigned int w[4];
#pragma unroll
    for (int d = 0; d < 4; d++) {
      unsigned int u0 = min(__float2uint_rn((c[4 * d + 0] - mn) * inv), 255u);
      unsigned int u1 = min(__float2uint_rn((c[4 * d + 1] - mn) * inv), 255u);
      unsigned int u2 = min(__float2uint_rn((c[4 * d + 2] - mn) * inv), 255u);
      unsigned int u3 = min(__float2uint_rn((c[4 * d + 3] - mn) * inv), 255u);
      w[d] = u0 | (u1 << 8) | (u2 << 16) | (u3 << 24);
    }
    *(uint4*)(dst + ((size_t)row << 10) + (lane << 4)) = make_uint4(w[0], w[1], w[2], w[3]);
    if (lane == 0) rowScale[(q << 10) + row] = make_float2(mn, scale);
  }
}

// ---- phase 1c: column stats for the transposed copies ----
__global__ __launch_bounds__(256) void colminmax(const __half* __restrict__ Ch,
                                                 float4* __restrict__ pMn, float4* __restrict__ pMx) {
  const int blk = blockIdx.x;
  const int p = blk >> 3, rb = blk & 7;
  const int j0 = threadIdx.x << 2;
  const __half* src = Ch + ((size_t)p << 20) + j0;
  float mn[4] = {3.4e38f, 3.4e38f, 3.4e38f, 3.4e38f};
  float mx[4] = {-3.4e38f, -3.4e38f, -3.4e38f, -3.4e38f};
  for (int r = 0; r < 128; r++) {
    const int row = (rb << 7) + r;
    uint2 raw = *(const uint2*)(src + ((size_t)row << 10));
    const __half2* hh = (const __half2*)&raw;
    float2 f0 = __half22float2(hh[0]);
    float2 f1 = __half22float2(hh[1]);
    float v[4] = {f0.x, f0.y, f1.x, f1.y};
#pragma unroll
    for (int t = 0; t < 4; t++) { mn[t] = fminf(mn[t], v[t]); mx[t] = fmaxf(mx[t], v[t]); }
  }
  const int o = ((p << 3) + rb) * 256 + threadIdx.x;
  pMn[o] = make_float4(mn[0], mn[1], mn[2], mn[3]);
  pMx[o] = make_float4(mx[0], mx[1], mx[2], mx[3]);
}

__global__ void colreduce(const float4* __restrict__ pMn, const float4* __restrict__ pMx,
                          float2* __restrict__ rowScale) {
  const int id = blockIdx.x * 256 + threadIdx.x;   // 28*256
  const int p = id >> 8, t = id & 255;
  float4 mn = pMn[(p << 3) * 256 + t];
  float4 mx = pMx[(p << 3) * 256 + t];
  for (int rb = 1; rb < 8; rb++) {
    float4 a = pMn[((p << 3) + rb) * 256 + t];
    float4 b = pMx[((p << 3) + rb) * 256 + t];
    mn.x = fminf(mn.x, a.x); mn.y = fminf(mn.y, a.y); mn.z = fminf(mn.z, a.z); mn.w = fminf(mn.w, a.w);
    mx.x = fmaxf(mx.x, b.x); mx.y = fmaxf(mx.y, b.y); mx.z = fmaxf(mx.z, b.z); mx.w = fmaxf(mx.w, b.w);
  }
  const int qT = 8 * c_pb[p] + c_pa[p];
  float bs[4] = {mn.x, mn.y, mn.z, mn.w};
  float xs[4] = {mx.x, mx.y, mx.z, mx.w};
#pragma unroll
  for (int cc = 0; cc < 4; cc++) {
    float range = xs[cc] - bs[cc];
    float scale = (range > 1e-6f) ? range * (1.0f / 255.0f) : 1.0f;
    rowScale[(qT << 10) + (t << 2) + cc] = make_float2(bs[cc], scale);
  }
}

// ---- phase 1d: transpose + quantize into the mate slot ----
__global__ __launch_bounds__(256) void quantT(const __half* __restrict__ Ch,
                                              const float2* __restrict__ rowScale,
                                              unsigned char* __restrict__ C8) {
  __shared__ __half t[64][72];
  const int blk = blockIdx.x;            // p*256 + tile
  const int p = blk >> 8, tb = blk & 255;
  const int i0 = (tb >> 4) << 6, j0 = (tb & 15) << 6;
  const int qT = 8 * c_pb[p] + c_pa[p];
  const __half* src = Ch + ((size_t)p << 20);
  unsigned char* dst = C8 + ((size_t)qT << 20);
  const int tid = threadIdx.x;
  const int r = tid >> 2, cg = (tid & 3) << 4;
  const float4* s4 = (const float4*)(src + ((size_t)(i0 + r) << 10) + j0 + cg);
  float4 v0 = s4[0], v1 = s4[1];
  *(float4*)&t[r][cg] = v0;
  *(float4*)&t[r][cg + 8] = v1;
  __syncthreads();
  const int jr = j0 + r;                 // dest row
  const float2 sc = rowScale[(qT << 10) + jr];
  const float inv = 1.0f / sc.y;
  unsigned int w[4];
#pragma unroll
  for (int d = 0; d < 4; d++) {
    unsigned int uu[4];
#pragma unroll
    for (int e = 0; e < 4; e++) {
      float c = __half2float(t[cg + 4 * d + e][r]);
      uu[e] = min(__float2uint_rn((c - sc.x) * inv), 255u);
    }
    w[d] = uu[0] | (uu[1] << 8) | (uu[2] << 16) | (uu[3] << 24);
  }
  *(uint4*)(dst + ((size_t)jr << 10) + i0 + cg) = make_uint4(w[0], w[1], w[2], w[3]);
}

// ---- phase 2: one Sinkhorn step = 64 row-softmins over u8 C. LDS-free streaming. ----
// XCD swizzle: blockIdx i -> x=i&7 (XCD), r=i>>3; q=((r&7)<<3)|x, chunk=r>>3.
__global__ __launch_bounds__(256) void sink_step(
    const unsigned char* __restrict__ C8, const float2* __restrict__ rowScale,
    const float* __restrict__ pot_cur, float* __restrict__ pot_nxt,
    float eps, float csS, float cmS) {
  const int i = blockIdx.x;
  const int x = i & 7, rr = i >> 3;
  const int q = ((rr & 7) << 3) | x;
  const int chunk = rr >> 3;
  const int mate = ((q & 7) << 3) | (q >> 3);
  const bool diag = (mate == q);
  const float cs = diag ? csS : 0.f;
  const float cm = diag ? cmS : 1.f;
  const int wave = threadIdx.x >> 6, lane = threadIdx.x & 63;
  const float* hp = pot_cur + (mate << 10) + (lane << 4);
  float h[16];
  {
    float4 h0 = ((const float4*)hp)[0], h1 = ((const float4*)hp)[1];
    float4 h2 = ((const float4*)hp)[2], h3 = ((const float4*)hp)[3];
    h[0]=h0.x; h[1]=h0.y; h[2]=h0.z; h[3]=h0.w;
    h[4]=h1.x; h[5]=h1.y; h[6]=h1.z; h[7]=h1.w;
    h[8]=h2.x; h[9]=h2.y; h[10]=h2.z; h[11]=h2.w;
    h[12]=h3.x; h[13]=h3.y; h[14]=h3.z; h[15]=h3.w;
  }
  const float c0 = LOG2E / eps;
  const unsigned char* Cb = C8 + ((size_t)q << 20) + ((size_t)chunk << 15) + (lane << 4);

  for (int k = 0; k < 8; k++) {
    const int lr = (k << 2) + wave;
    const int row = (chunk << 5) + lr;
    const uint4 uv = *(const uint4*)(Cb + ((size_t)lr << 10));
    const float2 rs = rowScale[(q << 10) + row];
    const float ns = -rs.y;
    float a[16];
#pragma unroll
    for (int d = 0; d < 4; d++) {
      const unsigned int w = (&uv.x)[d];
      a[4 * d + 0] = fmaf(ub(w, 0),  ns, h[4 * d + 0] - rs.x);
      a[4 * d + 1] = fmaf(ub(w, 8),  ns, h[4 * d + 1] - rs.x);
      a[4 * d + 2] = fmaf(ub(w, 16), ns, h[4 * d + 2] - rs.x);
      a[4 * d + 3] = fmaf(ub(w, 24), ns, h[4 * d + 3] - rs.x);
    }
    float m = a[0];
#pragma unroll
    for (int t = 1; t < 16; t++) m = fmaxf(m, a[t]);
    m = wredMax(m);
    float ss = 0.f;
#pragma unroll
    for (int t = 0; t < 16; t++) ss += exp2f((a[t] - m) * c0);  // subtract-first: exact at max
    ss = wredSum(ss);
    if (lane == 0) {
      const float sm = -(m + eps * (__logf(ss) - LOG_N));
      pot_nxt[(q << 10) + row] = cs * pot_cur[(q << 10) + row] + cm * sm;
    }
  }
}

// ---- phase 3: losses ----
__global__ void loss_pairs(const float* __restrict__ pot, float* __restrict__ out) {
  int pb = blockIdx.x;
  int si = c_pa[pb], sj = c_pb[pb];
  const float* fv = pot + ((8 * si + sj) << 10);
  const float* gv = pot + ((8 * sj + si) << 10);
  const float* sa = pot + ((9 * si) << 10);
  const float* sb = pot + ((9 * sj) << 10);
  float acc = 0.f;
  for (int t = threadIdx.x; t < NPT; t += 256)
    acc += (fv[t] - sa[t]) + (gv[t] - sb[t]);
  acc = wredSum(acc);
  __shared__ float wsm[4];
  if ((threadIdx.x & 63) == 0) wsm[threadIdx.x >> 6] = acc;
  __syncthreads();
  if (threadIdx.x == 0) out[1 + pb] = (wsm[0] + wsm[1] + wsm[2] + wsm[3]) * (1.0f / NPT);
}

__global__ void loss_total(float* __restrict__ out) {
  int t = threadIdx.x;
  float x = (t < NPAIR) ? out[1 + t] : 0.f;
  x = wredSum(x);
  if (t == 0) out[0] = x / (float)NPAIR;
}

extern "C" void kernel_launch(void* const* d_in, const int* in_sizes, int n_in,
                              void* d_out, int out_size, void* d_ws, size_t ws_size,
                              hipStream_t stream) {
  const float* feat = (const float*)d_in[0];
  const int* sg = (const int*)d_in[1];
  float* out = (float*)d_out;
  char* ws = (char*)d_ws;

  size_t o = 0;
  __half* Ch = (__half*)(ws + o); o += (size_t)NBLK * NPT * NPT * 2;      // 72 MB (fp16 staging)
  unsigned char* C8 = (unsigned char*)(ws + o); o += (size_t)64 * NPT * NPT; // 64 MB (u8, both orientations)
  float2* rowScale = (float2*)(ws + o); o += (size_t)64 * NPT * 8;        // 512 KB
  float4* pMn = (float4*)(ws + o); o += (size_t)NPAIR * 8 * 256 * 16;     // 0.9 MB
  float4* pMx = (float4*)(ws + o); o += (size_t)NPAIR * 8 * 256 * 16;
  float* G  = (float*)(ws + o); o += (size_t)NROW * DIM * 4;              // 8.4 MB
  float* sq = (float*)(ws + o); o += (size_t)NROW * 4;
  int* idx  = (int*)(ws + o); o += (size_t)NROW * 4;
  int* cnt  = (int*)(ws + o); o += 1024;
  float* pot[2];
  pot[0] = (float*)(ws + o); o += (size_t)64 * NPT * 4;
  pot[1] = (float*)(ws + o); o += (size_t)64 * NPT * 4;

  hipMemsetAsync(cnt, 0, 1024, stream);
  hipMemsetAsync(pot[0], 0, (size_t)64 * NPT * 4, stream);   // f0=g0=s0=0

  build_idx<<<NROW / 256, 256, 0, stream>>>(sg, idx, cnt);
  gather_rows<<<NROW, 256, 0, stream>>>(feat, idx, G, sq);
  cost_gemm<<<NBLK * 64, 256, 0, stream>>>(G, sq, Ch);
  quant_row<<<NBLK * 16, 256, 0, stream>>>(Ch, C8, rowScale);
  colminmax<<<NPAIR * 8, 256, 0, stream>>>(Ch, pMn, pMx);
  colreduce<<<NPAIR, 256, 0, stream>>>(pMn, pMx, rowScale);
  quantT<<<NPAIR * 256, 256, 0, stream>>>(Ch, rowScale, C8);

  // epsilon schedule (mirrors reference trace-time logic)
  float sched[256];
  int ns = 0;
  {
    double e = 256.0;
    const double ratio = 0.9 * 0.9;
    const double tgt = 1e-4 * 1e-4;
    while (e > tgt) { sched[ns++] = (float)e; e *= ratio; }
    sched[ns++] = (float)tgt;
  }
  const float epsT = sched[ns - 1];

  int cur = 0;
  for (int k = 0; k < ns; k++) {
    sink_step<<<64 * 32, 256, 0, stream>>>(C8, rowScale, pot[cur], pot[1 - cur],
                                           sched[k], 0.5f, 0.5f);
    cur ^= 1;
  }
  // final extrapolation at eps_target (diag not blended)
  sink_step<<<64 * 32, 256, 0, stream>>>(C8, rowScale, pot[cur], pot[1 - cur],
                                         epsT, 0.0f, 1.0f);
  cur ^= 1;
  loss_pairs<<<NPAIR, 256, 0, stream>>>(pot[cur], out);
  loss_total<<<1, 64, 0, stream>>>(out);
}

// Round 9
// 3215.368 us; speedup vs baseline: 1.4955x; 1.0803x over previous
//
#include <hip/hip_runtime.h>
#include <hip/hip_fp16.h>
#include <cstddef>
#include <cstdint>

#define NSG   8
#define NPAIR 28
#define NBLK  36                 // unique cost products: 28 cross + 8 self
#define NPT   1024
#define DIM   256
#define NROW  8192
#define LOG_N  6.9314718055994531f
#define LOG2E  1.4426950408889634f

// triu_indices(8,1) pairs, then 8 self pairs
__constant__ int c_pa[NBLK] = {0,0,0,0,0,0,0,1,1,1,1,1,1,2,2,2,2,2,3,3,3,3,4,4,4,5,5,6, 0,1,2,3,4,5,6,7};
__constant__ int c_pb[NBLK] = {1,2,3,4,5,6,7,2,3,4,5,6,7,3,4,5,6,7,4,5,6,7,5,6,7,6,7,7, 0,1,2,3,4,5,6,7};

__device__ __forceinline__ float wredMax(float v) {
#pragma unroll
  for (int o = 32; o > 0; o >>= 1) v = fmaxf(v, __shfl_xor(v, o, 64));
  return v;
}
__device__ __forceinline__ float wredMin(float v) {
#pragma unroll
  for (int o = 32; o > 0; o >>= 1) v = fminf(v, __shfl_xor(v, o, 64));
  return v;
}
__device__ __forceinline__ float wredSum(float v) {
#pragma unroll
  for (int o = 32; o > 0; o >>= 1) v += __shfl_xor(v, o, 64);
  return v;
}

__device__ __forceinline__ void cvt16(float4 A, float4 B, float* c) {
  const __half2* ha = (const __half2*)&A;
  const __half2* hb = (const __half2*)&B;
#pragma unroll
  for (int i = 0; i < 4; i++) {
    float2 f = __half22float2(ha[i]);
    c[2 * i] = f.x; c[2 * i + 1] = f.y;
  }
#pragma unroll
  for (int i = 0; i < 4; i++) {
    float2 f = __half22float2(hb[i]);
    c[8 + 2 * i] = f.x; c[8 + 2 * i + 1] = f.y;
  }
}

__device__ __forceinline__ float ub(unsigned int w, int s) {
  return (float)((w >> s) & 0xffu);   // v_cvt_f32_ubyteN
}

// ---- phase 0: grouping ----
__global__ void build_idx(const int* __restrict__ sg, int* __restrict__ idx, int* __restrict__ cnt) {
  int i = blockIdx.x * 256 + threadIdx.x;
  if (i >= NROW) return;
  int s = sg[i];
  int r = atomicAdd(&cnt[s], 1);
  idx[s * NPT + r] = i;
}

__global__ void gather_rows(const float* __restrict__ feat, const int* __restrict__ idx,
                            float* __restrict__ G, float* __restrict__ sq) {
  int row = blockIdx.x;
  int src = idx[row];
  float v = feat[(size_t)src * DIM + threadIdx.x];
  G[(size_t)row * DIM + threadIdx.x] = v;
  float p = wredSum(v * v);
  __shared__ float ws[4];
  if ((threadIdx.x & 63) == 0) ws[threadIdx.x >> 6] = p;
  __syncthreads();
  if (threadIdx.x == 0) sq[row] = 0.5f * (ws[0] + ws[1] + ws[2] + ws[3]);
}

// ---- phase 1: cost matrices (fp16) into Ch[b], b = unique product idx ----
__global__ __launch_bounds__(256) void cost_gemm(const float* __restrict__ G,
                                                 const float* __restrict__ sq,
                                                 __half* __restrict__ Ch) {
  __shared__ float As[8][128];
  __shared__ float Bt[8][128];
  int blk = blockIdx.x;
  int b = blk >> 6, t = blk & 63;
  int sa = c_pa[b], sb = c_pb[b];
  int i0 = (t >> 3) << 7, j0 = (t & 7) << 7;
  const float* Arows = G + (size_t)(sa * NPT + i0) * DIM;
  const float* Brows = G + (size_t)(sb * NPT + j0) * DIM;
  int tid = threadIdx.x;
  int ty = tid >> 4, tx = tid & 15;
  float acc[8][8];
#pragma unroll
  for (int r = 0; r < 8; r++)
#pragma unroll
    for (int q = 0; q < 8; q++) acc[r][q] = 0.f;

  int lrow = tid >> 1, lk4 = (tid & 1) << 2;
  for (int k0 = 0; k0 < DIM; k0 += 8) {
    __syncthreads();
    float4 av = *(const float4*)(Arows + (size_t)lrow * DIM + k0 + lk4);
    float4 bv = *(const float4*)(Brows + (size_t)lrow * DIM + k0 + lk4);
    As[lk4 + 0][lrow] = av.x; As[lk4 + 1][lrow] = av.y; As[lk4 + 2][lrow] = av.z; As[lk4 + 3][lrow] = av.w;
    Bt[lk4 + 0][lrow] = bv.x; Bt[lk4 + 1][lrow] = bv.y; Bt[lk4 + 2][lrow] = bv.z; Bt[lk4 + 3][lrow] = bv.w;
    __syncthreads();
#pragma unroll
    for (int kk = 0; kk < 8; kk++) {
      float4 a0 = *(const float4*)&As[kk][ty << 3];
      float4 a1 = *(const float4*)&As[kk][(ty << 3) + 4];
      float4 b0 = *(const float4*)&Bt[kk][tx << 3];
      float4 b1 = *(const float4*)&Bt[kk][(tx << 3) + 4];
      float ar[8] = {a0.x, a0.y, a0.z, a0.w, a1.x, a1.y, a1.z, a1.w};
      float br[8] = {b0.x, b0.y, b0.z, b0.w, b1.x, b1.y, b1.z, b1.w};
#pragma unroll
      for (int r = 0; r < 8; r++)
#pragma unroll
        for (int q = 0; q < 8; q++) acc[r][q] = fmaf(ar[r], br[q], acc[r][q]);
    }
  }
  __half* dst = Ch + ((size_t)b << 20);
  float sqa[8], sqb[8];
#pragma unroll
  for (int r = 0; r < 8; r++) sqa[r] = sq[sa * NPT + i0 + (ty << 3) + r];
#pragma unroll
  for (int q = 0; q < 8; q++) sqb[q] = sq[sb * NPT + j0 + (tx << 3) + q];
#pragma unroll
  for (int r = 0; r < 8; r++) {
    __half* drow = dst + (size_t)(i0 + (ty << 3) + r) * NPT + j0 + (tx << 3);
    union { float4 f4; __half h[8]; } o;
#pragma unroll
    for (int q = 0; q < 8; q++)
      o.h[q] = __float2half_rn(fmaxf(sqa[r] + sqb[q] - acc[r][q], 0.f));
    *(float4*)drow = o.f4;
  }
}

// ---- phase 1b: per-row u8 quantization into C8 slot (q = 8a+b layout; diag = 9a) ----
__global__ __launch_bounds__(256) void quant_row(const __half* __restrict__ Ch,
                                                 unsigned char* __restrict__ C8,
                                                 float2* __restrict__ rowScale) {
  const int blk = blockIdx.x;
  const int b = blk >> 4, rowblk = blk & 15;
  const int sa = c_pa[b], sb = c_pb[b];
  const int q = (sa == sb) ? 9 * sa : 8 * sa + sb;
  const __half* src = Ch + ((size_t)b << 20);
  unsigned char* dst = C8 + ((size_t)q << 20);
  const int wave = threadIdx.x >> 6, lane = threadIdx.x & 63;
  for (int jj = 0; jj < 16; jj++) {
    const int row = (rowblk << 6) + (jj << 2) + wave;
    const float4* s4 = (const float4*)(src + ((size_t)row << 10) + (lane << 4));
    float c[16];
    cvt16(s4[0], s4[1], c);
    float mn = c[0], mx = c[0];
#pragma unroll
    for (int t = 1; t < 16; t++) { mn = fminf(mn, c[t]); mx = fmaxf(mx, c[t]); }
    mn = wredMin(mn);
    mx = wredMax(mx);
    const float range = mx - mn;
    const float scale = (range > 1e-6f) ? range * (1.0f / 255.0f) : 1.0f;
    const float inv = (range > 1e-6f) ? 255.0f / range : 0.0f;
    unsigned int w[4];
#pragma unroll
    for (int d = 0; d < 4; d++) {
      unsigned int u0 = min(__float2uint_rn((c[4 * d + 0] - mn) * inv), 255u);
      unsigned int u1 = min(__float2uint_rn((c[4 * d + 1] - mn) * inv), 255u);
      unsigned int u2 = min(__float2uint_rn((c[4 * d + 2] - mn) * inv), 255u);
      unsigned int u3 = min(__float2uint_rn((c[4 * d + 3] - mn) * inv), 255u);
      w[d] = u0 | (u1 << 8) | (u2 << 16) | (u3 << 24);
    }
    *(uint4*)(dst + ((size_t)row << 10) + (lane << 4)) = make_uint4(w[0], w[1], w[2], w[3]);
    if (lane == 0) rowScale[(q << 10) + row] = make_float2(mn, scale);
  }
}

// ---- phase 1c: column stats for the transposed copies ----
__global__ __launch_bounds__(256) void colminmax(const __half* __restrict__ Ch,
                                                 float4* __restrict__ pMn, float4* __restrict__ pMx) {
  const int blk = blockIdx.x;
  const int p = blk >> 3, rb = blk & 7;
  const int j0 = threadIdx.x << 2;
  const __half* src = Ch + ((size_t)p << 20) + j0;
  float mn[4] = {3.4e38f, 3.4e38f, 3.4e38f, 3.4e38f};
  float mx[4] = {-3.4e38f, -3.4e38f, -3.4e38f, -3.4e38f};
  for (int r = 0; r < 128; r++) {
    const int row = (rb << 7) + r;
    uint2 raw = *(const uint2*)(src + ((size_t)row << 10));
    const __half2* hh = (const __half2*)&raw;
    float2 f0 = __half22float2(hh[0]);
    float2 f1 = __half22float2(hh[1]);
    float v[4] = {f0.x, f0.y, f1.x, f1.y};
#pragma unroll
    for (int t = 0; t < 4; t++) { mn[t] = fminf(mn[t], v[t]); mx[t] = fmaxf(mx[t], v[t]); }
  }
  const int o = ((p << 3) + rb) * 256 + threadIdx.x;
  pMn[o] = make_float4(mn[0], mn[1], mn[2], mn[3]);
  pMx[o] = make_float4(mx[0], mx[1], mx[2], mx[3]);
}

__global__ void colreduce(const float4* __restrict__ pMn, const float4* __restrict__ pMx,
                          float2* __restrict__ rowScale) {
  const int id = blockIdx.x * 256 + threadIdx.x;   // 28*256
  const int p = id >> 8, t = id & 255;
  float4 mn = pMn[(p << 3) * 256 + t];
  float4 mx = pMx[(p << 3) * 256 + t];
  for (int rb = 1; rb < 8; rb++) {
    float4 a = pMn[((p << 3) + rb) * 256 + t];
    float4 b = pMx[((p << 3) + rb) * 256 + t];
    mn.x = fminf(mn.x, a.x); mn.y = fminf(mn.y, a.y); mn.z = fminf(mn.z, a.z); mn.w = fminf(mn.w, a.w);
    mx.x = fmaxf(mx.x, b.x); mx.y = fmaxf(mx.y, b.y); mx.z = fmaxf(mx.z, b.z); mx.w = fmaxf(mx.w, b.w);
  }
  const int qT = 8 * c_pb[p] + c_pa[p];
  float bs[4] = {mn.x, mn.y, mn.z, mn.w};
  float xs[4] = {mx.x, mx.y, mx.z, mx.w};
#pragma unroll
  for (int cc = 0; cc < 4; cc++) {
    float range = xs[cc] - bs[cc];
    float scale = (range > 1e-6f) ? range * (1.0f / 255.0f) : 1.0f;
    rowScale[(qT << 10) + (t << 2) + cc] = make_float2(bs[cc], scale);
  }
}

// ---- phase 1d: transpose + quantize into the mate slot ----
__global__ __launch_bounds__(256) void quantT(const __half* __restrict__ Ch,
                                              const float2* __restrict__ rowScale,
                                              unsigned char* __restrict__ C8) {
  __shared__ __half t[64][72];
  const int blk = blockIdx.x;            // p*256 + tile
  const int p = blk >> 8, tb = blk & 255;
  const int i0 = (tb >> 4) << 6, j0 = (tb & 15) << 6;
  const int qT = 8 * c_pb[p] + c_pa[p];
  const __half* src = Ch + ((size_t)p << 20);
  unsigned char* dst = C8 + ((size_t)qT << 20);
  const int tid = threadIdx.x;
  const int r = tid >> 2, cg = (tid & 3) << 4;
  const float4* s4 = (const float4*)(src + ((size_t)(i0 + r) << 10) + j0 + cg);
  float4 v0 = s4[0], v1 = s4[1];
  *(float4*)&t[r][cg] = v0;
  *(float4*)&t[r][cg + 8] = v1;
  __syncthreads();
  const int jr = j0 + r;                 // dest row
  const float2 sc = rowScale[(qT << 10) + jr];
  const float inv = 1.0f / sc.y;
  unsigned int w[4];
#pragma unroll
  for (int d = 0; d < 4; d++) {
    unsigned int uu[4];
#pragma unroll
    for (int e = 0; e < 4; e++) {
      float c = __half2float(t[cg + 4 * d + e][r]);
      uu[e] = min(__float2uint_rn((c - sc.x) * inv), 255u);
    }
    w[d] = uu[0] | (uu[1] << 8) | (uu[2] << 16) | (uu[3] << 24);
  }
  *(uint4*)(dst + ((size_t)jr << 10) + i0 + cg) = make_uint4(w[0], w[1], w[2], w[3]);
}

// ---- phase 2: one Sinkhorn step = 64 row-softmins over u8 C. LDS-free streaming. ----
// LSE=true: exact softmin. LSE=false (eps < ~1e-3): softmin -> min, error <= eps*log n.
// All 8 row loads issued up-front (registers) to overlap memory with compute.
template <bool LSE>
__global__ __launch_bounds__(256) void sink_step(
    const unsigned char* __restrict__ C8, const float2* __restrict__ rowScale,
    const float* __restrict__ pot_cur, float* __restrict__ pot_nxt,
    float eps, float csS, float cmS) {
  const int i = blockIdx.x;
  const int x = i & 7, rr = i >> 3;
  const int q = ((rr & 7) << 3) | x;     // XCD swizzle: q's low 3 bits pinned to XCD
  const int chunk = rr >> 3;
  const int mate = ((q & 7) << 3) | (q >> 3);
  const bool diag = (mate == q);
  const float cs = diag ? csS : 0.f;
  const float cm = diag ? cmS : 1.f;
  const int wave = threadIdx.x >> 6, lane = threadIdx.x & 63;
  const float* hp = pot_cur + (mate << 10) + (lane << 4);
  float h[16];
  {
    float4 h0 = ((const float4*)hp)[0], h1 = ((const float4*)hp)[1];
    float4 h2 = ((const float4*)hp)[2], h3 = ((const float4*)hp)[3];
    h[0]=h0.x; h[1]=h0.y; h[2]=h0.z; h[3]=h0.w;
    h[4]=h1.x; h[5]=h1.y; h[6]=h1.z; h[7]=h1.w;
    h[8]=h2.x; h[9]=h2.y; h[10]=h2.z; h[11]=h2.w;
    h[12]=h3.x; h[13]=h3.y; h[14]=h3.z; h[15]=h3.w;
  }
  const float c0 = LOG2E / eps;
  const unsigned char* Cb = C8 + ((size_t)q << 20) + ((size_t)chunk << 15) + (lane << 4);

  // issue all 8 row loads before any compute
  uint4 uv[8];
#pragma unroll
  for (int k = 0; k < 8; k++)
    uv[k] = *(const uint4*)(Cb + ((size_t)((k << 2) + wave) << 10));

#pragma unroll
  for (int k = 0; k < 8; k++) {
    const int row = (chunk << 5) + (k << 2) + wave;
    const float2 rs = rowScale[(q << 10) + row];
    const float ns = -rs.y;
    float a[16];
#pragma unroll
    for (int d = 0; d < 4; d++) {
      const unsigned int w = (&uv[k].x)[d];
      a[4 * d + 0] = fmaf(ub(w, 0),  ns, h[4 * d + 0] - rs.x);
      a[4 * d + 1] = fmaf(ub(w, 8),  ns, h[4 * d + 1] - rs.x);
      a[4 * d + 2] = fmaf(ub(w, 16), ns, h[4 * d + 2] - rs.x);
      a[4 * d + 3] = fmaf(ub(w, 24), ns, h[4 * d + 3] - rs.x);
    }
    float m = a[0];
#pragma unroll
    for (int t = 1; t < 16; t++) m = fmaxf(m, a[t]);
    m = wredMax(m);
    float sm;
    if (LSE) {
      float ss = 0.f;
#pragma unroll
      for (int t = 0; t < 16; t++) ss += exp2f((a[t] - m) * c0);  // subtract-first: exact at max
      ss = wredSum(ss);
      sm = -(m + eps * (__logf(ss) - LOG_N));
    } else {
      sm = -m;   // softmin -> min as eps -> 0; |err| <= eps*log n
    }
    if (lane == 0)
      pot_nxt[(q << 10) + row] = cs * pot_cur[(q << 10) + row] + cm * sm;
  }
}

// ---- phase 3: losses ----
__global__ void loss_pairs(const float* __restrict__ pot, float* __restrict__ out) {
  int pb = blockIdx.x;
  int si = c_pa[pb], sj = c_pb[pb];
  const float* fv = pot + ((8 * si + sj) << 10);
  const float* gv = pot + ((8 * sj + si) << 10);
  const float* sa = pot + ((9 * si) << 10);
  const float* sb = pot + ((9 * sj) << 10);
  float acc = 0.f;
  for (int t = threadIdx.x; t < NPT; t += 256)
    acc += (fv[t] - sa[t]) + (gv[t] - sb[t]);
  acc = wredSum(acc);
  __shared__ float wsm[4];
  if ((threadIdx.x & 63) == 0) wsm[threadIdx.x >> 6] = acc;
  __syncthreads();
  if (threadIdx.x == 0) out[1 + pb] = (wsm[0] + wsm[1] + wsm[2] + wsm[3]) * (1.0f / NPT);
}

__global__ void loss_total(float* __restrict__ out) {
  int t = threadIdx.x;
  float x = (t < NPAIR) ? out[1 + t] : 0.f;
  x = wredSum(x);
  if (t == 0) out[0] = x / (float)NPAIR;
}

extern "C" void kernel_launch(void* const* d_in, const int* in_sizes, int n_in,
                              void* d_out, int out_size, void* d_ws, size_t ws_size,
                              hipStream_t stream) {
  const float* feat = (const float*)d_in[0];
  const int* sg = (const int*)d_in[1];
  float* out = (float*)d_out;
  char* ws = (char*)d_ws;

  size_t o = 0;
  __half* Ch = (__half*)(ws + o); o += (size_t)NBLK * NPT * NPT * 2;      // 72 MB (fp16 staging)
  unsigned char* C8 = (unsigned char*)(ws + o); o += (size_t)64 * NPT * NPT; // 64 MB (u8, both orientations)
  float2* rowScale = (float2*)(ws + o); o += (size_t)64 * NPT * 8;        // 512 KB
  float4* pMn = (float4*)(ws + o); o += (size_t)NPAIR * 8 * 256 * 16;     // 0.9 MB
  float4* pMx = (float4*)(ws + o); o += (size_t)NPAIR * 8 * 256 * 16;
  float* G  = (float*)(ws + o); o += (size_t)NROW * DIM * 4;              // 8.4 MB
  float* sq = (float*)(ws + o); o += (size_t)NROW * 4;
  int* idx  = (int*)(ws + o); o += (size_t)NROW * 4;
  int* cnt  = (int*)(ws + o); o += 1024;
  float* pot[2];
  pot[0] = (float*)(ws + o); o += (size_t)64 * NPT * 4;
  pot[1] = (float*)(ws + o); o += (size_t)64 * NPT * 4;

  hipMemsetAsync(cnt, 0, 1024, stream);
  hipMemsetAsync(pot[0], 0, (size_t)64 * NPT * 4, stream);   // f0=g0=s0=0

  build_idx<<<NROW / 256, 256, 0, stream>>>(sg, idx, cnt);
  gather_rows<<<NROW, 256, 0, stream>>>(feat, idx, G, sq);
  cost_gemm<<<NBLK * 64, 256, 0, stream>>>(G, sq, Ch);
  quant_row<<<NBLK * 16, 256, 0, stream>>>(Ch, C8, rowScale);
  colminmax<<<NPAIR * 8, 256, 0, stream>>>(Ch, pMn, pMx);
  colreduce<<<NPAIR, 256, 0, stream>>>(pMn, pMx, rowScale);
  quantT<<<NPAIR * 256, 256, 0, stream>>>(Ch, rowScale, C8);

  // epsilon schedule (mirrors reference trace-time logic)
  float sched[256];
  int ns = 0;
  {
    double e = 256.0;
    const double ratio = 0.9 * 0.9;
    const double tgt = 1e-4 * 1e-4;
    while (e > tgt) { sched[ns++] = (float)e; e *= ratio; }
    sched[ns++] = (float)tgt;
  }
  const float epsT = sched[ns - 1];
  const float EPS_CUT = 1e-3f;   // below this, softmin==min to within eps*log(n) ~ 7e-3

  int cur = 0;
  for (int k = 0; k < ns; k++) {
    if (sched[k] >= EPS_CUT)
      sink_step<true><<<64 * 32, 256, 0, stream>>>(C8, rowScale, pot[cur], pot[1 - cur],
                                                   sched[k], 0.5f, 0.5f);
    else
      sink_step<false><<<64 * 32, 256, 0, stream>>>(C8, rowScale, pot[cur], pot[1 - cur],
                                                    sched[k], 0.5f, 0.5f);
    cur ^= 1;
  }
  // final extrapolation at eps_target (diag not blended); epsT=1e-8 -> min form
  sink_step<false><<<64 * 32, 256, 0, stream>>>(C8, rowScale, pot[cur], pot[1 - cur],
                                                epsT, 0.0f, 1.0f);
  cur ^= 1;
  loss_pairs<<<NPAIR, 256, 0, stream>>>(pot[cur], out);
  loss_total<<<1, 64, 0, stream>>>(out);
}